// Round 1
// baseline (27285.257 us; speedup 1.0000x reference)
//
#include <hip/hip_runtime.h>

// Problem: 4-layer LSTM decoder. B=64, T=64, H=1024, V=32000, E=512.
// Round 1: correct baseline. fp32 recurrence (VALU), bf16 MFMA for the big FC.
// d_in: 0 idx[B][T] int32; 1..8 h1,c1..h4,c4 [64][1024] f32; 9 emb [V][E];
//       10+3l W,U,b per layer; 22 Wfc [1024][32000]; 23 bfc [32000].

#define B_ 64
#define T_ 64
#define H_ 1024
#define V_ 32000
#define E_ 512

typedef short v8s __attribute__((ext_vector_type(8)));
typedef float v4f __attribute__((ext_vector_type(4)));

__device__ inline unsigned short f2bf(float f) {
    unsigned u = __float_as_uint(f);
    u += 0x7fffu + ((u >> 16) & 1u);
    return (unsigned short)(u >> 16);
}

// ---------------- gather: X[t][b][e] = emb[idx[b][t]][e] ----------------
__global__ __launch_bounds__(256) void gather_embed(const int* __restrict__ idx,
                                                    const float* __restrict__ emb,
                                                    float* __restrict__ X) {
    int g = blockIdx.x * 256 + threadIdx.x;  // float4 index, 524288 total (grid 2048)
    int roww = g >> 7;                       // row = t*64 + b (128 float4 per row)
    int off = g & 127;
    int t = roww >> 6, b = roww & 63;
    int v = idx[b * T_ + t];
    ((float4*)X)[g] = ((const float4*)(emb + (size_t)v * E_))[off];
}

// ---------------- init h/c state ----------------
__global__ __launch_bounds__(256) void init_state(const float* h1, const float* c1,
                                                  const float* h2, const float* c2,
                                                  const float* h3, const float* c3,
                                                  const float* h4, const float* c4,
                                                  float* __restrict__ hbuf,
                                                  float* __restrict__ cbuf) {
    int y = blockIdx.y;           // 0..7
    int layer = y >> 1, isc = y & 1;
    const float* src = h1;
    switch (y) { case 0: src = h1; break; case 1: src = c1; break;
                 case 2: src = h2; break; case 3: src = c2; break;
                 case 4: src = h3; break; case 5: src = c3; break;
                 case 6: src = h4; break; case 7: src = c4; break; }
    int g = blockIdx.x * 256 + threadIdx.x;  // 16384 float4 per array (grid.x 64)
    float4 v = ((const float4*)src)[g];
    float* dst = isc ? (cbuf + layer * (B_ * H_)) : (hbuf + layer * 2 * (B_ * H_)); // h -> slot 0
    ((float4*)dst)[g] = v;
}

// ---------------- Wfc fp32 -> bf16 ----------------
__global__ __launch_bounds__(256) void conv_wfc(const float* __restrict__ src,
                                                unsigned short* __restrict__ dst) {
    size_t g = (size_t)blockIdx.x * 256 + threadIdx.x;  // 8 elems each; grid 16000
    float4 a = ((const float4*)src)[g * 2];
    float4 b = ((const float4*)src)[g * 2 + 1];
    union { uint4 v; unsigned short s[8]; } o;
    o.s[0] = f2bf(a.x); o.s[1] = f2bf(a.y); o.s[2] = f2bf(a.z); o.s[3] = f2bf(a.w);
    o.s[4] = f2bf(b.x); o.s[5] = f2bf(b.y); o.s[6] = f2bf(b.z); o.s[7] = f2bf(b.w);
    ((uint4*)dst)[g] = o.v;
}

// ---------------- fused LSTM layer step: z = x@W + h@U + b, cell, h/c update ---
// grid (64, 4): blockIdx.x = 16-col tile of H, blockIdx.y = 16-row tile of B.
// thread (r=tid>>4, c=tid&15) computes the 4 gate dots for (row0+r, hcol).
__global__ __launch_bounds__(256) void lstm_layer_kernel(
    const float* __restrict__ x, int KX,              // [64][KX]
    const float* __restrict__ W,                      // [KX][4096]
    const float* __restrict__ U,                      // [1024][4096]
    const float* __restrict__ bias,                   // [4096]
    const float* __restrict__ hin,                    // [64][1024]
    float* __restrict__ hout,                         // [64][1024]
    float* __restrict__ cbuf,                         // [64][1024] (in-place safe)
    unsigned short* __restrict__ h4out)               // nullable, bf16 [64][1024]
{
    __shared__ float As[16][36];   // 36: 16B-aligned rows, conflict-free
    __shared__ float Ws[32][65];
    const int tid = threadIdx.x;
    const int r = tid >> 4, cth = tid & 15;
    const int row0 = blockIdx.y * 16;
    const int hcol = blockIdx.x * 16 + cth;
    float acc0 = 0.f, acc1 = 0.f, acc2 = 0.f, acc3 = 0.f;
    const int Ktot = KX + H_;
    for (int k0 = 0; k0 < Ktot; k0 += 32) {
        {   // A tile [16][32]
            int e = tid;
            #pragma unroll
            for (int it = 0; it < 2; ++it, e += 256) {
                int i = e >> 5, kk = e & 31;
                int kg = k0 + kk;
                float v = (kg < KX) ? x[(row0 + i) * KX + kg]
                                    : hin[(row0 + i) * H_ + (kg - KX)];
                As[i][kk] = v;
            }
        }
        {   // W tile [32][64]: cc = gate*16 + c -> global col gate*H + bx*16 + c
            int e = tid;
            #pragma unroll
            for (int it = 0; it < 8; ++it, e += 256) {
                int kk = e >> 6, cc = e & 63;
                int col = (cc >> 4) * H_ + blockIdx.x * 16 + (cc & 15);
                int kg = k0 + kk;
                float v = (kg < KX) ? W[(size_t)kg * (4 * H_) + col]
                                    : U[(size_t)(kg - KX) * (4 * H_) + col];
                Ws[kk][cc] = v;
            }
        }
        __syncthreads();
        #pragma unroll
        for (int kk = 0; kk < 32; ++kk) {
            float a = As[r][kk];
            acc0 = fmaf(a, Ws[kk][cth], acc0);
            acc1 = fmaf(a, Ws[kk][16 + cth], acc1);
            acc2 = fmaf(a, Ws[kk][32 + cth], acc2);
            acc3 = fmaf(a, Ws[kk][48 + cth], acc3);
        }
        __syncthreads();
    }
    const int row = row0 + r;
    float zi = acc0 + bias[hcol];
    float zf = acc1 + bias[H_ + hcol];
    float zg = acc2 + bias[2 * H_ + hcol];
    float zo = acc3 + bias[3 * H_ + hcol];
    float c_old = cbuf[row * H_ + hcol];
    float si = 1.f / (1.f + __expf(-zi));
    float sf = 1.f / (1.f + __expf(-zf));
    float so = 1.f / (1.f + __expf(-zo));
    float tg = tanhf(zg);
    float cn = sf * c_old + si * tg;
    float hn = so * tanhf(cn);
    cbuf[row * H_ + hcol] = cn;
    hout[row * H_ + hcol] = hn;
    if (h4out) h4out[row * H_ + hcol] = f2bf(hn);
}

// ---------------- FC GEMM: logits = h4a(bf16) @ Wfc(bf16) + bfc -> d_out -----
// A rows ra = t*64+b; output row ro = b*64+t (reference output is [B][T][V]).
// Block tile 64(M) x 128(N), BK=32, 4 waves each own 16 M-rows.
__global__ __launch_bounds__(256) void fc_gemm(const unsigned short* __restrict__ A,
                                               const unsigned short* __restrict__ Bw,
                                               const float* __restrict__ bfc,
                                               float* __restrict__ out) {
    __shared__ unsigned short As[64][40];   // +8 pad -> 80B rows: 2-way (free)
    __shared__ unsigned short Bs[128][40];  // stored transposed: Bs[n][k]
    const int tid = threadIdx.x;
    const int w = tid >> 6, l = tid & 63;
    const int q = l >> 4, ln = l & 15;
    const int mBlock = blockIdx.y * 64;
    const int nBlock = blockIdx.x * 128;
    v4f acc[8];
    #pragma unroll
    for (int j = 0; j < 8; ++j) acc[j] = (v4f){0.f, 0.f, 0.f, 0.f};
    const int ai = tid >> 2, au = tid & 3;
    for (int k0 = 0; k0 < H_; k0 += 32) {
        uint4 av = ((const uint4*)A)[(size_t)(mBlock + ai) * (H_ / 8) + (k0 >> 3) + au];
        int e0 = tid, e1 = tid + 256;
        int kk0 = e0 >> 4, nj0 = e0 & 15;
        int kk1 = e1 >> 4, nj1 = e1 & 15;
        union { uint4 v; unsigned short s[8]; } b0, b1;
        b0.v = ((const uint4*)Bw)[(size_t)(k0 + kk0) * (V_ / 8) + (nBlock >> 3) + nj0];
        b1.v = ((const uint4*)Bw)[(size_t)(k0 + kk1) * (V_ / 8) + (nBlock >> 3) + nj1];
        __syncthreads();   // prior iteration's frag reads done
        *(uint4*)&As[ai][au * 8] = av;
        #pragma unroll
        for (int s = 0; s < 8; ++s) Bs[nj0 * 8 + s][kk0] = b0.s[s];
        #pragma unroll
        for (int s = 0; s < 8; ++s) Bs[nj1 * 8 + s][kk1] = b1.s[s];
        __syncthreads();
        v8s afr = *(const v8s*)&As[w * 16 + ln][q * 8];
        #pragma unroll
        for (int j = 0; j < 8; ++j) {
            v8s bfr = *(const v8s*)&Bs[j * 16 + ln][q * 8];
            acc[j] = __builtin_amdgcn_mfma_f32_16x16x32_bf16(afr, bfr, acc[j], 0, 0, 0);
        }
    }
    #pragma unroll
    for (int j = 0; j < 8; ++j) {
        int n = nBlock + j * 16 + ln;
        float bias = bfc[n];
        #pragma unroll
        for (int rr = 0; rr < 4; ++rr) {
            int ra = mBlock + w * 16 + q * 4 + rr;           // t*64+b
            int ro = ((ra & 63) << 6) | (ra >> 6);           // b*64+t
            out[(size_t)ro * V_ + n] = acc[j][rr] + bias;
        }
    }
}

// ---------------- softmax: stats then normalize (in-place on d_out) ----------
__global__ __launch_bounds__(256) void softmax_stats(const float* __restrict__ out,
                                                     float* __restrict__ stats) {
    __shared__ float red[256];
    int ro = blockIdx.x;
    const float* row = out + (size_t)ro * V_;
    int tid = threadIdx.x;
    float m = -3.4e38f;
    for (int i = tid; i < V_; i += 256) m = fmaxf(m, row[i]);
    red[tid] = m; __syncthreads();
    for (int s = 128; s; s >>= 1) {
        if (tid < s) red[tid] = fmaxf(red[tid], red[tid + s]);
        __syncthreads();
    }
    float M = red[0];
    __syncthreads();
    float l = 0.f;
    for (int i = tid; i < V_; i += 256) l += __expf(row[i] - M);
    red[tid] = l; __syncthreads();
    for (int s = 128; s; s >>= 1) {
        if (tid < s) red[tid] += red[tid + s];
        __syncthreads();
    }
    if (tid == 0) { stats[ro * 2] = M; stats[ro * 2 + 1] = 1.f / red[0]; }
}

__global__ __launch_bounds__(256) void softmax_norm(float* __restrict__ out,
                                                    const float* __restrict__ stats) {
    int ro = blockIdx.y;
    int slot = blockIdx.x * 256 + threadIdx.x;  // grid.x = 32 -> 8192 slots, 8000 used
    if (slot >= V_ / 4) return;
    float M = stats[ro * 2], inv = stats[ro * 2 + 1];
    float4* p = (float4*)(out + (size_t)ro * V_);
    float4 v = p[slot];
    v.x = __expf(v.x - M) * inv;
    v.y = __expf(v.y - M) * inv;
    v.z = __expf(v.z - M) * inv;
    v.w = __expf(v.w - M) * inv;
    p[slot] = v;
}

extern "C" void kernel_launch(void* const* d_in, const int* in_sizes, int n_in,
                              void* d_out, int out_size, void* d_ws, size_t ws_size,
                              hipStream_t stream) {
    const int* idx = (const int*)d_in[0];
    const float* h0[4] = {(const float*)d_in[1], (const float*)d_in[3],
                          (const float*)d_in[5], (const float*)d_in[7]};
    const float* c0[4] = {(const float*)d_in[2], (const float*)d_in[4],
                          (const float*)d_in[6], (const float*)d_in[8]};
    const float* emb = (const float*)d_in[9];
    const float* W[4], *U[4], *bb[4];
    for (int l = 0; l < 4; ++l) {
        W[l]  = (const float*)d_in[10 + 3 * l];
        U[l]  = (const float*)d_in[11 + 3 * l];
        bb[l] = (const float*)d_in[12 + 3 * l];
    }
    const float* Wfc = (const float*)d_in[22];
    const float* bfc = (const float*)d_in[23];
    float* out = (float*)d_out;

    // ws layout (bytes): Xbuf 8MB | hbuf 2MB | cbuf 1MB | h4a 8MB | wfcb 62.5MB | stats
    char* ws = (char*)d_ws;
    float* Xbuf = (float*)ws;                                    // [T][B][E] f32
    float* hbuf = (float*)(ws + 8388608);                        // [4][2][64][1024] f32
    float* cbuf = (float*)(ws + 10485760);                       // [4][64][1024] f32
    unsigned short* h4a  = (unsigned short*)(ws + 11534336);     // [T*B][H] bf16
    unsigned short* wfcb = (unsigned short*)(ws + 19922944);     // [H][V] bf16
    float* stats = (float*)(ws + 85458944);                      // [4096][2]

    gather_embed<<<2048, 256, 0, stream>>>(idx, emb, Xbuf);
    init_state<<<dim3(64, 8), 256, 0, stream>>>(h0[0], c0[0], h0[1], c0[1],
                                                h0[2], c0[2], h0[3], c0[3], hbuf, cbuf);
    conv_wfc<<<16000, 256, 0, stream>>>(Wfc, wfcb);

    const int SL = B_ * H_;  // 65536 floats per state slot
    for (int t = 0; t < T_; ++t) {
        int p = t & 1, q = p ^ 1;  // read slot p, write slot q (double-buffered h)
        lstm_layer_kernel<<<dim3(64, 4), 256, 0, stream>>>(
            Xbuf + (size_t)t * (B_ * E_), E_, W[0], U[0], bb[0],
            hbuf + (0 * 2 + p) * SL, hbuf + (0 * 2 + q) * SL, cbuf + 0 * SL, nullptr);
        for (int l = 1; l < 4; ++l) {
            unsigned short* h4o = (l == 3) ? (h4a + (size_t)t * (B_ * H_)) : nullptr;
            lstm_layer_kernel<<<dim3(64, 4), 256, 0, stream>>>(
                hbuf + ((l - 1) * 2 + q) * SL, H_, W[l], U[l], bb[l],
                hbuf + (l * 2 + p) * SL, hbuf + (l * 2 + q) * SL, cbuf + l * SL, h4o);
        }
    }

    fc_gemm<<<dim3(V_ / 128, (T_ * B_) / 64), 256, 0, stream>>>(h4a, wfcb, bfc, out);
    softmax_stats<<<T_ * B_, 256, 0, stream>>>(out, stats);
    softmax_norm<<<dim3(32, T_ * B_), 256, 0, stream>>>(out, stats);
}